// Round 1
// baseline (1858.711 us; speedup 1.0000x reference)
//
#include <hip/hip_runtime.h>

constexpr int NPIX = 4096;   // H*W = 64*64
constexpr int NB   = 2;      // batch

// ---------------------------------------------------------------------------
// conv1x1: y[b,d,n] = bias[d] + sum_c x[b,c,n] * w[c,d]
// 4 output channels per thread; grid = (NPIX/256, Co/4, NB)
// ---------------------------------------------------------------------------
__global__ __launch_bounds__(256) void conv1x1_k(
    const float* __restrict__ x, const float* __restrict__ w,
    const float* __restrict__ bias, float* __restrict__ y, int Ci, int Co) {
  int n  = blockIdx.x * 256 + threadIdx.x;
  int d0 = blockIdx.y * 4;
  int b  = blockIdx.z;
  float a0, a1, a2, a3;
  if (bias) { a0 = bias[d0 + 0]; a1 = bias[d0 + 1]; a2 = bias[d0 + 2]; a3 = bias[d0 + 3]; }
  else      { a0 = a1 = a2 = a3 = 0.f; }
  const float* xb = x + ((size_t)b * Ci) * NPIX + n;
  const float* wr = w + d0;
  for (int c = 0; c < Ci; ++c) {
    float xv = xb[(size_t)c * NPIX];
    a0 += xv * wr[0];
    a1 += xv * wr[1];
    a2 += xv * wr[2];
    a3 += xv * wr[3];
    wr += Co;
  }
  float* yb = y + ((size_t)b * Co + d0) * NPIX + n;
  yb[0]            = a0;
  yb[NPIX]         = a1;
  yb[2 * (size_t)NPIX] = a2;
  yb[3 * (size_t)NPIX] = a3;
}

// ---------------------------------------------------------------------------
// BN stats: one block per channel; biased var over (B, N)
// ---------------------------------------------------------------------------
__global__ __launch_bounds__(256) void bn_stats_k(
    const float* __restrict__ y, float* __restrict__ mean, float* __restrict__ rstd, int C) {
  int c = blockIdx.x;
  int tid = threadIdx.x;
  float s = 0.f, s2 = 0.f;
  for (int i = tid; i < NB * NPIX; i += 256) {
    int b = i >> 12;            // NPIX = 4096
    int n = i & (NPIX - 1);
    float v = y[((size_t)b * C + c) * NPIX + n];
    s  += v;
    s2 += v * v;
  }
  __shared__ float sh0[256];
  __shared__ float sh1[256];
  sh0[tid] = s; sh1[tid] = s2;
  __syncthreads();
  for (int st = 128; st > 0; st >>= 1) {
    if (tid < st) { sh0[tid] += sh0[tid + st]; sh1[tid] += sh1[tid + st]; }
    __syncthreads();
  }
  if (tid == 0) {
    const float inv = 1.f / (NB * NPIX);
    float m = sh0[0] * inv;
    float var = sh1[0] * inv - m * m;
    mean[c] = m;
    rstd[c] = rsqrtf(var + 1e-5f);
  }
}

// ---------------------------------------------------------------------------
// BN apply + ReLU (elementwise)
// ---------------------------------------------------------------------------
__global__ __launch_bounds__(256) void bn_apply_k(
    const float* __restrict__ y, const float* __restrict__ mean, const float* __restrict__ rstd,
    const float* __restrict__ g, const float* __restrict__ bb, float* __restrict__ out, int C) {
  int i = blockIdx.x * 256 + threadIdx.x;
  int c = (i >> 12) % C;
  float v = (y[i] - mean[c]) * rstd[c] * g[c] + bb[c];
  out[i] = v > 0.f ? v : 0.f;
}

// ---------------------------------------------------------------------------
// Attention partial: one thread per query n, m-chunked flash softmax.
// Two passes within chunk: (1) row max, (2) exp-sum + weighted h accumulate.
// g/h loads are wave-uniform (address independent of threadIdx) -> scalar loads.
// ---------------------------------------------------------------------------
template <int CF, int CO>
__global__ __launch_bounds__(64) void attn_partial_k(
    const float* __restrict__ f, const float* __restrict__ g,
    const float* __restrict__ h, float* __restrict__ pacc, float* __restrict__ pml,
    int clen) {
  int n  = blockIdx.x * 64 + threadIdx.x;
  int ch = blockIdx.y;
  int b  = blockIdx.z;
  const float* fb = f + (size_t)b * CF * NPIX;
  const float* gb = g + (size_t)b * CF * NPIX;
  const float* hb = h + (size_t)b * CO * NPIX;

  float fr[CF];
#pragma unroll
  for (int c = 0; c < CF; ++c) fr[c] = fb[(size_t)c * NPIX + n];

  const int m0 = ch * clen;

  // pass 1: chunk max (unroll x2 for ILP on the dependent dot chain)
  float mmax = -1e30f;
  for (int m = m0; m < m0 + clen; m += 2) {
    float s0 = 0.f, s1 = 0.f;
#pragma unroll
    for (int c = 0; c < CF; ++c) {
      s0 += fr[c] * gb[(size_t)c * NPIX + m];
      s1 += fr[c] * gb[(size_t)c * NPIX + m + 1];
    }
    mmax = fmaxf(mmax, fmaxf(s0, s1));
  }

  // pass 2: exp-sum + accumulate o partials
  float lsum = 0.f;
  float acc[CO];
#pragma unroll
  for (int c = 0; c < CO; ++c) acc[c] = 0.f;

  for (int m = m0; m < m0 + clen; ++m) {
    float s = 0.f;
#pragma unroll
    for (int c = 0; c < CF; ++c) s += fr[c] * gb[(size_t)c * NPIX + m];
    float p = __expf(s - mmax);
    lsum += p;
#pragma unroll
    for (int c = 0; c < CO; ++c) acc[c] += p * hb[(size_t)c * NPIX + m];
  }

  constexpr int Q = NB * NPIX;
  int q = b * NPIX + n;
  pml[((size_t)ch * Q + q) * 2 + 0] = mmax;
  pml[((size_t)ch * Q + q) * 2 + 1] = lsum;
  float* pa = pacc + ((size_t)ch * Q + q) * CO;
#pragma unroll
  for (int c = 0; c < CO; ++c) pa[c] = acc[c];
}

// ---------------------------------------------------------------------------
// Attention combine: merge chunk partials, divide, residual + gamma.
// grid = B*NPIX blocks, CO threads.
// ---------------------------------------------------------------------------
template <int CO>
__global__ void attn_combine_k(
    const float* __restrict__ pacc, const float* __restrict__ pml,
    const float* __restrict__ xhat, const float* __restrict__ gam,
    float* __restrict__ xout, int nch) {
  int q = blockIdx.x;      // b*NPIX + n
  int c = threadIdx.x;     // < CO
  constexpr int Q = NB * NPIX;
  float M = -1e30f;
  for (int ch = 0; ch < nch; ++ch) M = fmaxf(M, pml[((size_t)ch * Q + q) * 2]);
  float L = 0.f, o = 0.f;
  for (int ch = 0; ch < nch; ++ch) {
    float e = __expf(pml[((size_t)ch * Q + q) * 2] - M);
    L += e * pml[((size_t)ch * Q + q) * 2 + 1];
    o += e * pacc[((size_t)ch * Q + q) * CO + c];
  }
  o /= L;
  int b = q >> 12;
  int n = q & (NPIX - 1);
  size_t xi = ((size_t)b * CO + c) * NPIX + n;
  xout[xi] = gam[0] * o + xhat[xi];
}

// ---------------------------------------------------------------------------
// Final: BN apply + ReLU + global average pool. grid = (C, B), 256 threads.
// ---------------------------------------------------------------------------
__global__ __launch_bounds__(256) void bn_relu_gap_k(
    const float* __restrict__ y, const float* __restrict__ mean, const float* __restrict__ rstd,
    const float* __restrict__ g, const float* __restrict__ bb, float* __restrict__ out, int C) {
  int d = blockIdx.x;
  int b = blockIdx.y;
  int tid = threadIdx.x;
  const float* yr = y + ((size_t)b * C + d) * NPIX;
  float m = mean[d];
  float r = rstd[d] * g[d];
  float be = bb[d];
  float s = 0.f;
  for (int n = tid; n < NPIX; n += 256) {
    float v = (yr[n] - m) * r + be;
    s += v > 0.f ? v : 0.f;
  }
  __shared__ float sh[256];
  sh[tid] = s;
  __syncthreads();
  for (int st = 128; st > 0; st >>= 1) {
    if (tid < st) sh[tid] += sh[tid + st];
    __syncthreads();
  }
  if (tid == 0) out[(size_t)b * C + d] = sh[0] * (1.f / NPIX);
}

// ---------------------------------------------------------------------------
// Host side
// ---------------------------------------------------------------------------
static void launch_attn(int Co, const float* fb, const float* gb, const float* hb,
                        float* pacc, float* pml, const float* xh, const float* gam,
                        float* xo, int nch, hipStream_t s) {
  int clen = NPIX / nch;
  dim3 g(NPIX / 64, nch, NB);
  if (Co == 32) {
    attn_partial_k<4, 32><<<g, 64, 0, s>>>(fb, gb, hb, pacc, pml, clen);
    attn_combine_k<32><<<NB * NPIX, 32, 0, s>>>(pacc, pml, xh, gam, xo, nch);
  } else if (Co == 64) {
    attn_partial_k<8, 64><<<g, 64, 0, s>>>(fb, gb, hb, pacc, pml, clen);
    attn_combine_k<64><<<NB * NPIX, 64, 0, s>>>(pacc, pml, xh, gam, xo, nch);
  } else {
    attn_partial_k<12, 96><<<g, 64, 0, s>>>(fb, gb, hb, pacc, pml, clen);
    attn_combine_k<96><<<NB * NPIX, 96, 0, s>>>(pacc, pml, xh, gam, xo, nch);
  }
}

extern "C" void kernel_launch(void* const* d_in, const int* in_sizes, int n_in,
                              void* d_out, int out_size, void* d_ws, size_t ws_size,
                              hipStream_t stream) {
  const float* x    = (const float*)d_in[0];
  const float* wfin = (const float*)d_in[34];
  const float* bnfg = (const float*)d_in[35];
  const float* bnfb = (const float*)d_in[36];

  float* ws = (float*)d_ws;
  size_t off = 0;
  float* y    = ws + off; off += (size_t)NB * 512 * NPIX;   // conv output (max 512 ch)
  float* xh   = ws + off; off += (size_t)NB * 96 * NPIX;    // post BN+ReLU (attn input)
  float* xo   = ws + off; off += (size_t)NB * 96 * NPIX;    // attn output / next input
  float* fb   = ws + off; off += (size_t)NB * 12 * NPIX;
  float* gb   = ws + off; off += (size_t)NB * 12 * NPIX;
  float* hb   = ws + off; off += (size_t)NB * 96 * NPIX;
  float* mean = ws + off; off += 512;
  float* rstd = ws + off; off += 512;
  size_t base = off;

  // choose m-chunk count that fits ws (deterministic: ws_size fixed per session)
  int nch = 1;
  for (int cand = 8; cand >= 1; cand >>= 1) {
    size_t need = base + (size_t)cand * NB * NPIX * (2 + 96);
    if (need * sizeof(float) <= ws_size) { nch = cand; break; }
  }
  float* pml  = ws + base;
  float* pacc = pml + (size_t)nch * NB * NPIX * 2;

  const int Ci_arr[3] = {3, 32, 64};
  const int Co_arr[3] = {32, 64, 96};
  const float* cur = x;
  for (int i = 0; i < 3; ++i) {
    const float* const* p = (const float* const*)(d_in + 1 + i * 11);
    const float* w     = p[0];
    const float* bconv = p[1];
    const float* bg    = p[2];
    const float* bbeta = p[3];
    const float* awf   = p[4];
    const float* abf   = p[5];
    const float* awg   = p[6];
    const float* abg   = p[7];
    const float* awh   = p[8];
    const float* abh   = p[9];
    const float* gam   = p[10];
    int Ci = Ci_arr[i], Co = Co_arr[i], Cf = Co / 8;

    conv1x1_k<<<dim3(NPIX / 256, Co / 4, NB), 256, 0, stream>>>(cur, w, bconv, y, Ci, Co);
    bn_stats_k<<<Co, 256, 0, stream>>>(y, mean, rstd, Co);
    bn_apply_k<<<(NB * Co * NPIX) / 256, 256, 0, stream>>>(y, mean, rstd, bg, bbeta, xh, Co);

    conv1x1_k<<<dim3(NPIX / 256, Cf / 4, NB), 256, 0, stream>>>(xh, awf, abf, fb, Co, Cf);
    conv1x1_k<<<dim3(NPIX / 256, Cf / 4, NB), 256, 0, stream>>>(xh, awg, abg, gb, Co, Cf);
    conv1x1_k<<<dim3(NPIX / 256, Co / 4, NB), 256, 0, stream>>>(xh, awh, abh, hb, Co, Co);

    launch_attn(Co, fb, gb, hb, pacc, pml, xh, gam, xo, nch, stream);
    cur = xo;
  }

  // final conv (no bias) -> BN -> ReLU -> GAP
  conv1x1_k<<<dim3(NPIX / 256, 512 / 4, NB), 256, 0, stream>>>(cur, wfin, nullptr, y, 96, 512);
  bn_stats_k<<<512, 256, 0, stream>>>(y, mean, rstd, 512);
  bn_relu_gap_k<<<dim3(512, NB), 256, 0, stream>>>(y, mean, rstd, bnfg, bnfb, (float*)d_out, 512);
}

// Round 2
// 593.440 us; speedup vs baseline: 3.1321x; 3.1321x over previous
//
#include <hip/hip_runtime.h>

constexpr int NPIX = 4096;   // H*W = 64*64
constexpr int NB   = 2;      // batch
constexpr int NCH  = 8;      // m-chunks across blocks (ws-proven at this size)
constexpr int MLEN = NPIX / NCH;  // 512
constexpr int TM   = 64;     // m-tile staged in LDS
constexpr int QB   = 64;     // queries per block

// ---------------------------------------------------------------------------
// conv1x1: y[b,d,n] = bias[d] + sum_c x[b,c,n] * w[c,d]
// ---------------------------------------------------------------------------
__global__ __launch_bounds__(256) void conv1x1_k(
    const float* __restrict__ x, const float* __restrict__ w,
    const float* __restrict__ bias, float* __restrict__ y, int Ci, int Co) {
  int n  = blockIdx.x * 256 + threadIdx.x;
  int d0 = blockIdx.y * 4;
  int b  = blockIdx.z;
  float a0, a1, a2, a3;
  if (bias) { a0 = bias[d0 + 0]; a1 = bias[d0 + 1]; a2 = bias[d0 + 2]; a3 = bias[d0 + 3]; }
  else      { a0 = a1 = a2 = a3 = 0.f; }
  const float* xb = x + ((size_t)b * Ci) * NPIX + n;
  const float* wr = w + d0;
  for (int c = 0; c < Ci; ++c) {
    float xv = xb[(size_t)c * NPIX];
    a0 += xv * wr[0];
    a1 += xv * wr[1];
    a2 += xv * wr[2];
    a3 += xv * wr[3];
    wr += Co;
  }
  float* yb = y + ((size_t)b * Co + d0) * NPIX + n;
  yb[0]                = a0;
  yb[NPIX]             = a1;
  yb[2 * (size_t)NPIX] = a2;
  yb[3 * (size_t)NPIX] = a3;
}

// ---------------------------------------------------------------------------
// BN stats: one block per channel; biased var over (B, N)
// ---------------------------------------------------------------------------
__global__ __launch_bounds__(256) void bn_stats_k(
    const float* __restrict__ y, float* __restrict__ mean, float* __restrict__ rstd, int C) {
  int c = blockIdx.x;
  int tid = threadIdx.x;
  float s = 0.f, s2 = 0.f;
  for (int i = tid; i < NB * NPIX; i += 256) {
    int b = i >> 12;
    int n = i & (NPIX - 1);
    float v = y[((size_t)b * C + c) * NPIX + n];
    s  += v;
    s2 += v * v;
  }
  __shared__ float sh0[256];
  __shared__ float sh1[256];
  sh0[tid] = s; sh1[tid] = s2;
  __syncthreads();
  for (int st = 128; st > 0; st >>= 1) {
    if (tid < st) { sh0[tid] += sh0[tid + st]; sh1[tid] += sh1[tid + st]; }
    __syncthreads();
  }
  if (tid == 0) {
    const float inv = 1.f / (NB * NPIX);
    float m = sh0[0] * inv;
    float var = sh1[0] * inv - m * m;
    mean[c] = m;
    rstd[c] = rsqrtf(var + 1e-5f);
  }
}

// ---------------------------------------------------------------------------
// BN apply + ReLU (elementwise)
// ---------------------------------------------------------------------------
__global__ __launch_bounds__(256) void bn_apply_k(
    const float* __restrict__ y, const float* __restrict__ mean, const float* __restrict__ rstd,
    const float* __restrict__ g, const float* __restrict__ bb, float* __restrict__ out, int C) {
  int i = blockIdx.x * 256 + threadIdx.x;
  int c = (i >> 12) % C;
  float v = (y[i] - mean[c]) * rstd[c] * g[c] + bb[c];
  out[i] = v > 0.f ? v : 0.f;
}

// ---------------------------------------------------------------------------
// Attention partial v2: tiled LDS GEMM, no-max softmax (exp safe for |s|<60).
// Block = 256 threads, QB=64 queries, m-chunk = MLEN, m-tile = TM.
// Per tile: stage g/h -> P-phase (4 waves x 64 queries) -> GEMM phase
// (16x16 threads, each 4 q x CPT c register tile).
// ---------------------------------------------------------------------------
template <int CF, int CO>
__global__ __launch_bounds__(256) void attn_partial2_k(
    const float* __restrict__ f, const float* __restrict__ g,
    const float* __restrict__ h, float* __restrict__ pacc, float* __restrict__ pl) {
  constexpr int HS  = TM + 4;      // h_lds row stride (bank-spread, 16B-aligned)
  constexpr int CPT = CO / 16;     // channels per GEMM thread
  __shared__ __align__(16) float g_lds[CF][TM];
  __shared__ __align__(16) float h_lds[CO][HS];
  __shared__ __align__(16) float P_lds[TM][QB];
  __shared__ __align__(16) float l_lds[4][QB];

  const int t    = threadIdx.x;
  const int qblk = blockIdx.x;     // 0..NPIX/QB-1
  const int ch   = blockIdx.y;     // 0..NCH-1
  const int b    = blockIdx.z;

  const float* gb = g + ((size_t)b * CF) * NPIX;
  const float* hb = h + ((size_t)b * CO) * NPIX;

  // P-phase identity
  const int q  = t & 63;
  const int mg = t >> 6;           // wave id 0..3
  float fr[CF];
  {
    const float* fb = f + ((size_t)b * CF) * NPIX + qblk * QB + q;
#pragma unroll
    for (int c = 0; c < CF; ++c) fr[c] = fb[(size_t)c * NPIX];
  }

  // GEMM-phase identity
  const int qg = t & 15;           // query group (4 queries each)
  const int cg = t >> 4;           // channel group (CPT channels each)
  float acc[4][CPT];
#pragma unroll
  for (int i = 0; i < 4; ++i)
#pragma unroll
    for (int j = 0; j < CPT; ++j) acc[i][j] = 0.f;
  float lsum = 0.f;

  const int m0c = ch * MLEN;

  for (int tile = 0; tile < MLEN / TM; ++tile) {
    const int mt = m0c + tile * TM;
    __syncthreads();
    // stage g tile [CF][TM]
    for (int e = t; e < CF * (TM / 4); e += 256) {
      int row = e >> 4, m4 = (e & 15) << 2;
      float4 v = *(const float4*)(gb + (size_t)row * NPIX + mt + m4);
      *(float4*)&g_lds[row][m4] = v;
    }
    // stage h tile [CO][TM]
    for (int e = t; e < CO * (TM / 4); e += 256) {
      int row = e >> 4, m4 = (e & 15) << 2;
      float4 v = *(const float4*)(hb + (size_t)row * NPIX + mt + m4);
      *(float4*)&h_lds[row][m4] = v;
    }
    __syncthreads();
    // P phase: thread -> query q, local m range [mg*16, mg*16+16)
#pragma unroll
    for (int j0 = 0; j0 < 16; j0 += 4) {
      const int ml = mg * 16 + j0;
      float s0 = 0.f, s1 = 0.f, s2 = 0.f, s3 = 0.f;
#pragma unroll
      for (int c = 0; c < CF; ++c) {
        float4 gv = *(const float4*)&g_lds[c][ml];
        float fv = fr[c];
        s0 += fv * gv.x; s1 += fv * gv.y; s2 += fv * gv.z; s3 += fv * gv.w;
      }
      float p0 = __expf(fminf(s0, 60.f));
      float p1 = __expf(fminf(s1, 60.f));
      float p2 = __expf(fminf(s2, 60.f));
      float p3 = __expf(fminf(s3, 60.f));
      lsum += (p0 + p1) + (p2 + p3);
      P_lds[ml + 0][q] = p0;
      P_lds[ml + 1][q] = p1;
      P_lds[ml + 2][q] = p2;
      P_lds[ml + 3][q] = p3;
    }
    __syncthreads();
    // GEMM phase: acc[i][j] += P[m][qg*4+i] * h[cg*CPT+j][m]
#pragma unroll 2
    for (int m = 0; m < TM; ++m) {
      float4 pq = *(const float4*)&P_lds[m][qg << 2];
      const float pv[4] = {pq.x, pq.y, pq.z, pq.w};
      float hv[CPT];
#pragma unroll
      for (int j = 0; j < CPT; ++j) hv[j] = h_lds[cg * CPT + j][m];
#pragma unroll
      for (int i = 0; i < 4; ++i)
#pragma unroll
        for (int j = 0; j < CPT; ++j) acc[i][j] += pv[i] * hv[j];
    }
  }

  constexpr int Q = NB * NPIX;
  // combine per-query exp-sums across the 4 waves
  l_lds[mg][q] = lsum;
  __syncthreads();
  if (t < QB) {
    float L = l_lds[0][t] + l_lds[1][t] + l_lds[2][t] + l_lds[3][t];
    pl[(size_t)ch * Q + (size_t)b * NPIX + qblk * QB + t] = L;
  }
  float* pa = pacc + ((size_t)ch * Q + (size_t)b * NPIX + qblk * QB) * CO;
#pragma unroll
  for (int i = 0; i < 4; ++i)
#pragma unroll
    for (int j = 0; j < CPT; ++j)
      pa[(size_t)(qg * 4 + i) * CO + cg * CPT + j] = acc[i][j];
}

// ---------------------------------------------------------------------------
// Attention combine: sum chunk partials, divide by L, residual + gamma.
// ---------------------------------------------------------------------------
template <int CO>
__global__ void attn_combine2_k(
    const float* __restrict__ pacc, const float* __restrict__ pl,
    const float* __restrict__ xhat, const float* __restrict__ gam,
    float* __restrict__ xout) {
  int qI = blockIdx.x;     // b*NPIX + n
  int c  = threadIdx.x;    // < CO
  constexpr int Q = NB * NPIX;
  float L = 0.f, o = 0.f;
#pragma unroll
  for (int ch = 0; ch < NCH; ++ch) {
    L += pl[(size_t)ch * Q + qI];
    o += pacc[((size_t)ch * Q + qI) * CO + c];
  }
  o /= L;
  int b = qI >> 12;
  int n = qI & (NPIX - 1);
  size_t xi = ((size_t)b * CO + c) * NPIX + n;
  xout[xi] = gam[0] * o + xhat[xi];
}

// ---------------------------------------------------------------------------
// Final: BN apply + ReLU + global average pool. grid = (C, B), 256 threads.
// ---------------------------------------------------------------------------
__global__ __launch_bounds__(256) void bn_relu_gap_k(
    const float* __restrict__ y, const float* __restrict__ mean, const float* __restrict__ rstd,
    const float* __restrict__ g, const float* __restrict__ bb, float* __restrict__ out, int C) {
  int d = blockIdx.x;
  int b = blockIdx.y;
  int tid = threadIdx.x;
  const float* yr = y + ((size_t)b * C + d) * NPIX;
  float m = mean[d];
  float r = rstd[d] * g[d];
  float be = bb[d];
  float s = 0.f;
  for (int n = tid; n < NPIX; n += 256) {
    float v = (yr[n] - m) * r + be;
    s += v > 0.f ? v : 0.f;
  }
  __shared__ float sh[256];
  sh[tid] = s;
  __syncthreads();
  for (int st = 128; st > 0; st >>= 1) {
    if (tid < st) sh[tid] += sh[tid + st];
    __syncthreads();
  }
  if (tid == 0) out[(size_t)b * C + d] = sh[0] * (1.f / NPIX);
}

// ---------------------------------------------------------------------------
// Host side
// ---------------------------------------------------------------------------
static void launch_attn(int Co, const float* fb, const float* gb, const float* hb,
                        float* pacc, float* pl, const float* xh, const float* gam,
                        float* xo, hipStream_t s) {
  dim3 g(NPIX / QB, NCH, NB);
  if (Co == 32) {
    attn_partial2_k<4, 32><<<g, 256, 0, s>>>(fb, gb, hb, pacc, pl);
    attn_combine2_k<32><<<NB * NPIX, 32, 0, s>>>(pacc, pl, xh, gam, xo);
  } else if (Co == 64) {
    attn_partial2_k<8, 64><<<g, 256, 0, s>>>(fb, gb, hb, pacc, pl);
    attn_combine2_k<64><<<NB * NPIX, 64, 0, s>>>(pacc, pl, xh, gam, xo);
  } else {
    attn_partial2_k<12, 96><<<g, 256, 0, s>>>(fb, gb, hb, pacc, pl);
    attn_combine2_k<96><<<NB * NPIX, 96, 0, s>>>(pacc, pl, xh, gam, xo);
  }
}

extern "C" void kernel_launch(void* const* d_in, const int* in_sizes, int n_in,
                              void* d_out, int out_size, void* d_ws, size_t ws_size,
                              hipStream_t stream) {
  const float* x    = (const float*)d_in[0];
  const float* wfin = (const float*)d_in[34];
  const float* bnfg = (const float*)d_in[35];
  const float* bnfb = (const float*)d_in[36];

  float* ws = (float*)d_ws;
  size_t off = 0;
  float* y    = ws + off; off += (size_t)NB * 512 * NPIX;
  float* xh   = ws + off; off += (size_t)NB * 96 * NPIX;
  float* xo   = ws + off; off += (size_t)NB * 96 * NPIX;
  float* fb   = ws + off; off += (size_t)NB * 12 * NPIX;
  float* gb   = ws + off; off += (size_t)NB * 12 * NPIX;
  float* hb   = ws + off; off += (size_t)NB * 96 * NPIX;
  float* mean = ws + off; off += 512;
  float* rstd = ws + off; off += 512;
  float* pl   = ws + off; off += (size_t)NCH * NB * NPIX;
  float* pacc = ws + off; off += (size_t)NCH * NB * NPIX * 96;

  const int Ci_arr[3] = {3, 32, 64};
  const int Co_arr[3] = {32, 64, 96};
  const float* cur = x;
  for (int i = 0; i < 3; ++i) {
    const float* const* p = (const float* const*)(d_in + 1 + i * 11);
    const float* w     = p[0];
    const float* bconv = p[1];
    const float* bg    = p[2];
    const float* bbeta = p[3];
    const float* awf   = p[4];
    const float* abf   = p[5];
    const float* awg   = p[6];
    const float* abg   = p[7];
    const float* awh   = p[8];
    const float* abh   = p[9];
    const float* gam   = p[10];
    int Ci = Ci_arr[i], Co = Co_arr[i], Cf = Co / 8;

    conv1x1_k<<<dim3(NPIX / 256, Co / 4, NB), 256, 0, stream>>>(cur, w, bconv, y, Ci, Co);
    bn_stats_k<<<Co, 256, 0, stream>>>(y, mean, rstd, Co);
    bn_apply_k<<<(NB * Co * NPIX) / 256, 256, 0, stream>>>(y, mean, rstd, bg, bbeta, xh, Co);

    conv1x1_k<<<dim3(NPIX / 256, Cf / 4, NB), 256, 0, stream>>>(xh, awf, abf, fb, Co, Cf);
    conv1x1_k<<<dim3(NPIX / 256, Cf / 4, NB), 256, 0, stream>>>(xh, awg, abg, gb, Co, Cf);
    conv1x1_k<<<dim3(NPIX / 256, Co / 4, NB), 256, 0, stream>>>(xh, awh, abh, hb, Co, Co);

    launch_attn(Co, fb, gb, hb, pacc, pl, xh, gam, xo, stream);
    cur = xo;
  }

  conv1x1_k<<<dim3(NPIX / 256, 512 / 4, NB), 256, 0, stream>>>(cur, wfin, nullptr, y, 96, 512);
  bn_stats_k<<<512, 256, 0, stream>>>(y, mean, rstd, 512);
  bn_relu_gap_k<<<dim3(512, NB), 256, 0, stream>>>(y, mean, rstd, bnfg, bnfb, (float*)d_out, 512);
}

// Round 3
// 378.363 us; speedup vs baseline: 4.9125x; 1.5684x over previous
//
#include <hip/hip_runtime.h>
#include <hip/hip_bf16.h>

constexpr int NPIX = 4096;   // H*W
constexpr int NB   = 2;      // batch
constexpr int MS   = 2;      // m-split for attention
constexpr int QB   = 32;     // queries per attention block
constexpr int TM   = 64;     // m per wave-iteration
constexpr int PPITCH = 72;   // P_lds row pitch (bf16 elems): 2-way bank alias only

typedef __attribute__((ext_vector_type(8))) short bf16x8;
typedef __attribute__((ext_vector_type(4))) float f32x4;

// ---------------------------------------------------------------------------
// conv1x1 fp32: y[b,d,n] = bias[d] + sum_c x[b,c,n] * w[c,d]
// ---------------------------------------------------------------------------
__global__ __launch_bounds__(256) void conv1x1_k(
    const float* __restrict__ x, const float* __restrict__ w,
    const float* __restrict__ bias, float* __restrict__ y, int Ci, int Co) {
  int n  = blockIdx.x * 256 + threadIdx.x;
  int d0 = blockIdx.y * 4;
  int b  = blockIdx.z;
  float a0, a1, a2, a3;
  if (bias) { a0 = bias[d0 + 0]; a1 = bias[d0 + 1]; a2 = bias[d0 + 2]; a3 = bias[d0 + 3]; }
  else      { a0 = a1 = a2 = a3 = 0.f; }
  const float* xb = x + ((size_t)b * Ci) * NPIX + n;
  const float* wr = w + d0;
  for (int c = 0; c < Ci; ++c) {
    float xv = xb[(size_t)c * NPIX];
    a0 += xv * wr[0]; a1 += xv * wr[1]; a2 += xv * wr[2]; a3 += xv * wr[3];
    wr += Co;
  }
  float* yb = y + ((size_t)b * Co + d0) * NPIX + n;
  yb[0] = a0; yb[NPIX] = a1; yb[2 * (size_t)NPIX] = a2; yb[3 * (size_t)NPIX] = a3;
}

// ---------------------------------------------------------------------------
// conv1x1 -> bf16 output (for h)
// ---------------------------------------------------------------------------
__global__ __launch_bounds__(256) void conv_bf16_k(
    const float* __restrict__ x, const float* __restrict__ w,
    const float* __restrict__ bias, __hip_bfloat16* __restrict__ y, int Ci, int Co) {
  int n  = blockIdx.x * 256 + threadIdx.x;
  int d0 = blockIdx.y * 4;
  int b  = blockIdx.z;
  float a0 = bias[d0 + 0], a1 = bias[d0 + 1], a2 = bias[d0 + 2], a3 = bias[d0 + 3];
  const float* xb = x + ((size_t)b * Ci) * NPIX + n;
  const float* wr = w + d0;
  for (int c = 0; c < Ci; ++c) {
    float xv = xb[(size_t)c * NPIX];
    a0 += xv * wr[0]; a1 += xv * wr[1]; a2 += xv * wr[2]; a3 += xv * wr[3];
    wr += Co;
  }
  __hip_bfloat16* yb = y + ((size_t)b * Co + d0) * NPIX + n;
  yb[0]                = __float2bfloat16(a0);
  yb[NPIX]             = __float2bfloat16(a1);
  yb[2 * (size_t)NPIX] = __float2bfloat16(a2);
  yb[3 * (size_t)NPIX] = __float2bfloat16(a3);
}

// ---------------------------------------------------------------------------
// f & g convs fused, output transposed + channel-padded to 32: [B][N][32] bf16
// ---------------------------------------------------------------------------
template <int CF>
__global__ __launch_bounds__(256) void fg_convT_k(
    const float* __restrict__ xh, const float* __restrict__ wf, const float* __restrict__ bfv,
    const float* __restrict__ wg, const float* __restrict__ bgv,
    __hip_bfloat16* __restrict__ fqT, __hip_bfloat16* __restrict__ gqT, int Ci) {
  int n = blockIdx.x * 256 + threadIdx.x;
  int b = blockIdx.y;
  float fa[CF], ga[CF];
#pragma unroll
  for (int j = 0; j < CF; ++j) { fa[j] = bfv[j]; ga[j] = bgv[j]; }
  const float* xb = xh + ((size_t)b * Ci) * NPIX + n;
  for (int ci = 0; ci < Ci; ++ci) {
    float xv = xb[(size_t)ci * NPIX];
    const float* wfr = wf + (size_t)ci * CF;
    const float* wgr = wg + (size_t)ci * CF;
#pragma unroll
    for (int j = 0; j < CF; ++j) { fa[j] += xv * wfr[j]; ga[j] += xv * wgr[j]; }
  }
  __align__(16) __hip_bfloat16 of[32];
  __align__(16) __hip_bfloat16 og[32];
#pragma unroll
  for (int j = 0; j < 32; ++j) {
    of[j] = __float2bfloat16(j < CF ? fa[j] : 0.f);
    og[j] = __float2bfloat16(j < CF ? ga[j] : 0.f);
  }
  uint4* df = (uint4*)(fqT + ((size_t)b * NPIX + n) * 32);
  uint4* dg = (uint4*)(gqT + ((size_t)b * NPIX + n) * 32);
#pragma unroll
  for (int k = 0; k < 4; ++k) { df[k] = ((uint4*)of)[k]; dg[k] = ((uint4*)og)[k]; }
}

// ---------------------------------------------------------------------------
// BN stats
// ---------------------------------------------------------------------------
__global__ __launch_bounds__(256) void bn_stats_k(
    const float* __restrict__ y, float* __restrict__ mean, float* __restrict__ rstd, int C) {
  int c = blockIdx.x;
  int tid = threadIdx.x;
  float s = 0.f, s2 = 0.f;
  for (int i = tid; i < NB * NPIX; i += 256) {
    int b = i >> 12;
    int n = i & (NPIX - 1);
    float v = y[((size_t)b * C + c) * NPIX + n];
    s += v; s2 += v * v;
  }
  __shared__ float sh0[256];
  __shared__ float sh1[256];
  sh0[tid] = s; sh1[tid] = s2;
  __syncthreads();
  for (int st = 128; st > 0; st >>= 1) {
    if (tid < st) { sh0[tid] += sh0[tid + st]; sh1[tid] += sh1[tid + st]; }
    __syncthreads();
  }
  if (tid == 0) {
    const float inv = 1.f / (NB * NPIX);
    float m = sh0[0] * inv;
    float var = sh1[0] * inv - m * m;
    mean[c] = m;
    rstd[c] = rsqrtf(var + 1e-5f);
  }
}

// ---------------------------------------------------------------------------
// BN apply + ReLU
// ---------------------------------------------------------------------------
__global__ __launch_bounds__(256) void bn_apply_k(
    const float* __restrict__ y, const float* __restrict__ mean, const float* __restrict__ rstd,
    const float* __restrict__ g, const float* __restrict__ bb, float* __restrict__ out, int C) {
  int i = blockIdx.x * 256 + threadIdx.x;
  int c = (i >> 12) % C;
  float v = (y[i] - mean[c]) * rstd[c] * g[c] + bb[c];
  out[i] = v > 0.f ? v : 0.f;
}

// ---------------------------------------------------------------------------
// MFMA flash attention partial.
// fqT/gqT: [B][N][32] bf16 (c-padded); hq: [B][CO][N] bf16.
// Grid: (N/QB, MS, B), 256 threads (4 waves). Wave handles every 4th m-tile.
// Writes unnormalized pacc[ms][B*N][CO], pl[ms][B*N].
// ---------------------------------------------------------------------------
template <int CO>
__global__ __launch_bounds__(256, 2) void attn_mfma_k(
    const __hip_bfloat16* __restrict__ fqT, const __hip_bfloat16* __restrict__ gqT,
    const __hip_bfloat16* __restrict__ hq,
    float* __restrict__ pacc, float* __restrict__ pl) {
  constexpr int CSUB   = CO / 16;
  constexpr int OPITCH = CO + 1;
  constexpr int PBYTES = 4 * QB * PPITCH * 2;
  constexpr int OBYTES = 4 * QB * OPITCH * 4;
  constexpr int SBYTES = PBYTES > OBYTES ? PBYTES : OBYTES;
  __shared__ __align__(16) char smem[SBYTES];
  __shared__ float l_red[4][QB];
  unsigned short* Pw = (unsigned short*)smem;
  float* Ored = (float*)smem;

  const int t = threadIdx.x;
  const int wave = t >> 6, lane = t & 63, lq = lane & 15, lg = lane >> 4;
  const int qblk = blockIdx.x, ms = blockIdx.y, b = blockIdx.z;
  const int q0 = qblk * QB;

  // preload f B-fragments (col = lq = q, k-chunk by lg)
  bf16x8 ff[2];
#pragma unroll
  for (int qs = 0; qs < 2; ++qs)
    ff[qs] = *reinterpret_cast<const bf16x8*>(
        fqT + (((size_t)b * NPIX + q0 + qs * 16 + lq) << 5) + lg * 8);

  f32x4 acc[2][CSUB];
#pragma unroll
  for (int qs = 0; qs < 2; ++qs)
#pragma unroll
    for (int cs = 0; cs < CSUB; ++cs) acc[qs][cs] = f32x4{0.f, 0.f, 0.f, 0.f};
  float ls[2] = {0.f, 0.f};

  unsigned short* Pmy = Pw + wave * QB * PPITCH;
  const __hip_bfloat16* hbase = hq + ((size_t)b * CO + lq) * NPIX + lg * 8;

  const int mbeg = ms * (NPIX / MS) + wave * TM;
  const int mend = (ms + 1) * (NPIX / MS);
  for (int mt = mbeg; mt < mend; mt += 4 * TM) {
    // ---- QK: S[m][q] tiles, exp, P -> LDS ----
#pragma unroll
    for (int msub = 0; msub < 4; ++msub) {
      bf16x8 ga = *reinterpret_cast<const bf16x8*>(
          gqT + (((size_t)b * NPIX + mt + msub * 16 + lq) << 5) + lg * 8);
#pragma unroll
      for (int qs = 0; qs < 2; ++qs) {
        f32x4 z = {0.f, 0.f, 0.f, 0.f};
        f32x4 S = __builtin_amdgcn_mfma_f32_16x16x32_bf16(ga, ff[qs], z, 0, 0, 0);
        float p0 = __expf(fminf(S[0], 60.f));
        float p1 = __expf(fminf(S[1], 60.f));
        float p2 = __expf(fminf(S[2], 60.f));
        float p3 = __expf(fminf(S[3], 60.f));
        ls[qs] += (p0 + p1) + (p2 + p3);
        __hip_bfloat162 t0, t1;
        t0.x = __float2bfloat16(p0); t0.y = __float2bfloat16(p1);
        t1.x = __float2bfloat16(p2); t1.y = __float2bfloat16(p3);
        uint2 wv;
        wv.x = *(unsigned*)&t0; wv.y = *(unsigned*)&t1;
        // P_lds[q][m]: row = qs*16+lq, col = msub*16 + 4*lg (4 consecutive m)
        *(uint2*)(Pmy + (qs * 16 + lq) * PPITCH + msub * 16 + lg * 4) = wv;
      }
    }
    // ---- PV: O += P * h ----
#pragma unroll
    for (int kc = 0; kc < 2; ++kc) {
      bf16x8 pa[2];
#pragma unroll
      for (int qs = 0; qs < 2; ++qs)
        pa[qs] = *reinterpret_cast<const bf16x8*>(
            Pmy + (qs * 16 + lq) * PPITCH + kc * 32 + lg * 8);
      const __hip_bfloat16* hp = hbase + mt + kc * 32;
#pragma unroll
      for (int cs = 0; cs < CSUB; ++cs) {
        bf16x8 hv = *reinterpret_cast<const bf16x8*>(hp + (size_t)cs * 16 * NPIX);
#pragma unroll
        for (int qs = 0; qs < 2; ++qs)
          acc[qs][cs] = __builtin_amdgcn_mfma_f32_16x16x32_bf16(pa[qs], hv, acc[qs][cs], 0, 0, 0);
      }
    }
  }

  // per-q exp-sum: reduce across lane groups (m partials)
#pragma unroll
  for (int qs = 0; qs < 2; ++qs) {
    float l = ls[qs];
    l += __shfl_xor(l, 16);
    l += __shfl_xor(l, 32);
    ls[qs] = l;
  }

  __syncthreads();  // all waves done reading P before Ored overlay
  if (lane < 16) { l_red[wave][lq] = ls[0]; l_red[wave][16 + lq] = ls[1]; }
  // O D-frag: col = lq = c, row(q within 16) = 4*lg + r
#pragma unroll
  for (int qs = 0; qs < 2; ++qs)
#pragma unroll
    for (int cs = 0; cs < CSUB; ++cs)
#pragma unroll
      for (int r = 0; r < 4; ++r)
        Ored[((size_t)wave * QB + qs * 16 + 4 * lg + r) * OPITCH + cs * 16 + lq] = acc[qs][cs][r];
  __syncthreads();

  const size_t pbase = ((size_t)ms * NB + b) * NPIX + q0;
  for (int e = t; e < QB * CO; e += 256) {
    int q = e / CO, c = e - q * CO;
    float o = Ored[((size_t)0 * QB + q) * OPITCH + c] + Ored[((size_t)1 * QB + q) * OPITCH + c] +
              Ored[((size_t)2 * QB + q) * OPITCH + c] + Ored[((size_t)3 * QB + q) * OPITCH + c];
    pacc[(pbase + q) * (size_t)CO + c] = o;
  }
  if (t < QB) {
    pl[pbase + t] = l_red[0][t] + l_red[1][t] + l_red[2][t] + l_red[3][t];
  }
}

// ---------------------------------------------------------------------------
// Attention combine: sum m-split partials, divide by L, gamma + residual.
// ---------------------------------------------------------------------------
template <int CO>
__global__ void attn_combine2_k(
    const float* __restrict__ pacc, const float* __restrict__ pl,
    const float* __restrict__ xhat, const float* __restrict__ gam,
    float* __restrict__ xout) {
  int qI = blockIdx.x;
  int c  = threadIdx.x;
  constexpr int Q = NB * NPIX;
  float L = 0.f, o = 0.f;
#pragma unroll
  for (int m = 0; m < MS; ++m) {
    L += pl[(size_t)m * Q + qI];
    o += pacc[((size_t)m * Q + qI) * CO + c];
  }
  o /= L;
  int b = qI >> 12;
  int n = qI & (NPIX - 1);
  size_t xi = ((size_t)b * CO + c) * NPIX + n;
  xout[xi] = gam[0] * o + xhat[xi];
}

// ---------------------------------------------------------------------------
// Final: BN apply + ReLU + GAP
// ---------------------------------------------------------------------------
__global__ __launch_bounds__(256) void bn_relu_gap_k(
    const float* __restrict__ y, const float* __restrict__ mean, const float* __restrict__ rstd,
    const float* __restrict__ g, const float* __restrict__ bb, float* __restrict__ out, int C) {
  int d = blockIdx.x;
  int b = blockIdx.y;
  int tid = threadIdx.x;
  const float* yr = y + ((size_t)b * C + d) * NPIX;
  float m = mean[d];
  float r = rstd[d] * g[d];
  float be = bb[d];
  float s = 0.f;
  for (int n = tid; n < NPIX; n += 256) {
    float v = (yr[n] - m) * r + be;
    s += v > 0.f ? v : 0.f;
  }
  __shared__ float sh[256];
  sh[tid] = s;
  __syncthreads();
  for (int st = 128; st > 0; st >>= 1) {
    if (tid < st) sh[tid] += sh[tid + st];
    __syncthreads();
  }
  if (tid == 0) out[(size_t)b * C + d] = sh[0] * (1.f / NPIX);
}

// ---------------------------------------------------------------------------
// Host side
// ---------------------------------------------------------------------------
extern "C" void kernel_launch(void* const* d_in, const int* in_sizes, int n_in,
                              void* d_out, int out_size, void* d_ws, size_t ws_size,
                              hipStream_t stream) {
  const float* x    = (const float*)d_in[0];
  const float* wfin = (const float*)d_in[34];
  const float* bnfg = (const float*)d_in[35];
  const float* bnfb = (const float*)d_in[36];

  float* ws = (float*)d_ws;
  size_t off = 0;
  float* y    = ws + off; off += (size_t)NB * 512 * NPIX;
  float* xh   = ws + off; off += (size_t)NB * 96 * NPIX;
  float* xo   = ws + off; off += (size_t)NB * 96 * NPIX;
  __hip_bfloat16* fqT = (__hip_bfloat16*)(ws + off); off += (size_t)NB * NPIX * 16;
  __hip_bfloat16* gqT = (__hip_bfloat16*)(ws + off); off += (size_t)NB * NPIX * 16;
  __hip_bfloat16* hq  = (__hip_bfloat16*)(ws + off); off += (size_t)NB * 48 * NPIX;
  float* mean = ws + off; off += 512;
  float* rstd = ws + off; off += 512;
  float* pl   = ws + off; off += (size_t)MS * NB * NPIX;
  float* pacc = ws + off; off += (size_t)MS * NB * NPIX * 96;

  const int Ci_arr[3] = {3, 32, 64};
  const int Co_arr[3] = {32, 64, 96};
  const float* cur = x;
  for (int i = 0; i < 3; ++i) {
    const float* const* p = (const float* const*)(d_in + 1 + i * 11);
    const float* w     = p[0];
    const float* bconv = p[1];
    const float* bg    = p[2];
    const float* bbeta = p[3];
    const float* awf   = p[4];
    const float* abf   = p[5];
    const float* awg   = p[6];
    const float* abg   = p[7];
    const float* awh   = p[8];
    const float* abh   = p[9];
    const float* gam   = p[10];
    int Ci = Ci_arr[i], Co = Co_arr[i];

    conv1x1_k<<<dim3(NPIX / 256, Co / 4, NB), 256, 0, stream>>>(cur, w, bconv, y, Ci, Co);
    bn_stats_k<<<Co, 256, 0, stream>>>(y, mean, rstd, Co);
    bn_apply_k<<<(NB * Co * NPIX) / 256, 256, 0, stream>>>(y, mean, rstd, bg, bbeta, xh, Co);

    if (i == 0)      fg_convT_k<4><<<dim3(NPIX / 256, NB), 256, 0, stream>>>(xh, awf, abf, awg, abg, fqT, gqT, Co);
    else if (i == 1) fg_convT_k<8><<<dim3(NPIX / 256, NB), 256, 0, stream>>>(xh, awf, abf, awg, abg, fqT, gqT, Co);
    else             fg_convT_k<12><<<dim3(NPIX / 256, NB), 256, 0, stream>>>(xh, awf, abf, awg, abg, fqT, gqT, Co);

    conv_bf16_k<<<dim3(NPIX / 256, Co / 4, NB), 256, 0, stream>>>(xh, awh, abh, hq, Co, Co);

    dim3 ag(NPIX / QB, MS, NB);
    if (Co == 32) {
      attn_mfma_k<32><<<ag, 256, 0, stream>>>(fqT, gqT, hq, pacc, pl);
      attn_combine2_k<32><<<NB * NPIX, 32, 0, stream>>>(pacc, pl, xh, gam, xo);
    } else if (Co == 64) {
      attn_mfma_k<64><<<ag, 256, 0, stream>>>(fqT, gqT, hq, pacc, pl);
      attn_combine2_k<64><<<NB * NPIX, 64, 0, stream>>>(pacc, pl, xh, gam, xo);
    } else {
      attn_mfma_k<96><<<ag, 256, 0, stream>>>(fqT, gqT, hq, pacc, pl);
      attn_combine2_k<96><<<NB * NPIX, 96, 0, stream>>>(pacc, pl, xh, gam, xo);
    }
    cur = xo;
  }

  conv1x1_k<<<dim3(NPIX / 256, 512 / 4, NB), 256, 0, stream>>>(cur, wfin, nullptr, y, 96, 512);
  bn_stats_k<<<512, 256, 0, stream>>>(y, mean, rstd, 512);
  bn_relu_gap_k<<<dim3(512, NB), 256, 0, stream>>>(y, mean, rstd, bnfg, bnfb, (float*)d_out, 512);
}

// Round 4
// 255.434 us; speedup vs baseline: 7.2767x; 1.4813x over previous
//
#include <hip/hip_runtime.h>
#include <hip/hip_bf16.h>

constexpr int NPIX = 4096;   // H*W
constexpr int NB   = 2;      // batch
constexpr int MS   = 2;      // m-split for attention
constexpr int QB   = 32;     // queries per attention block
constexpr int TM   = 64;     // m per wave-iteration
constexpr int PPITCH = 72;   // P_lds row pitch (bf16): 2-way bank alias only (free)

typedef __attribute__((ext_vector_type(8))) short bf16x8;
typedef __attribute__((ext_vector_type(4))) float f32x4;

// ---------------------------------------------------------------------------
// conv1x1 fp32: 4-pixel float4 x 4-output-channel register tile per thread.
// grid = (NPIX/1024, Co/4, NB), 256 threads.
// ---------------------------------------------------------------------------
__global__ __launch_bounds__(256) void conv1x1_k(
    const float* __restrict__ x, const float* __restrict__ w,
    const float* __restrict__ bias, float* __restrict__ y, int Ci, int Co) {
  int n  = (blockIdx.x * 256 + threadIdx.x) * 4;
  int d0 = blockIdx.y * 4;
  int b  = blockIdx.z;
  float bv0 = 0.f, bv1 = 0.f, bv2 = 0.f, bv3 = 0.f;
  if (bias) { bv0 = bias[d0]; bv1 = bias[d0 + 1]; bv2 = bias[d0 + 2]; bv3 = bias[d0 + 3]; }
  float4 a0 = {bv0, bv0, bv0, bv0};
  float4 a1 = {bv1, bv1, bv1, bv1};
  float4 a2 = {bv2, bv2, bv2, bv2};
  float4 a3 = {bv3, bv3, bv3, bv3};
  const float* xb = x + ((size_t)b * Ci) * NPIX + n;
  const float* wr = w + d0;
#pragma unroll 2
  for (int c = 0; c < Ci; ++c) {
    float4 xv = *(const float4*)(xb + (size_t)c * NPIX);
    float w0 = wr[0], w1 = wr[1], w2 = wr[2], w3 = wr[3];
    a0.x += xv.x * w0; a0.y += xv.y * w0; a0.z += xv.z * w0; a0.w += xv.w * w0;
    a1.x += xv.x * w1; a1.y += xv.y * w1; a1.z += xv.z * w1; a1.w += xv.w * w1;
    a2.x += xv.x * w2; a2.y += xv.y * w2; a2.z += xv.z * w2; a2.w += xv.w * w2;
    a3.x += xv.x * w3; a3.y += xv.y * w3; a3.z += xv.z * w3; a3.w += xv.w * w3;
    wr += Co;
  }
  float* yb = y + ((size_t)b * Co + d0) * NPIX + n;
  *(float4*)(yb)                    = a0;
  *(float4*)(yb + NPIX)             = a1;
  *(float4*)(yb + 2 * (size_t)NPIX) = a2;
  *(float4*)(yb + 3 * (size_t)NPIX) = a3;
}

// ---------------------------------------------------------------------------
// conv1x1 -> bf16 output (for h), same tiling
// ---------------------------------------------------------------------------
__global__ __launch_bounds__(256) void conv_bf16_k(
    const float* __restrict__ x, const float* __restrict__ w,
    const float* __restrict__ bias, __hip_bfloat16* __restrict__ y, int Ci, int Co) {
  int n  = (blockIdx.x * 256 + threadIdx.x) * 4;
  int d0 = blockIdx.y * 4;
  int b  = blockIdx.z;
  float bv0 = bias[d0], bv1 = bias[d0 + 1], bv2 = bias[d0 + 2], bv3 = bias[d0 + 3];
  float4 a0 = {bv0, bv0, bv0, bv0};
  float4 a1 = {bv1, bv1, bv1, bv1};
  float4 a2 = {bv2, bv2, bv2, bv2};
  float4 a3 = {bv3, bv3, bv3, bv3};
  const float* xb = x + ((size_t)b * Ci) * NPIX + n;
  const float* wr = w + d0;
#pragma unroll 2
  for (int c = 0; c < Ci; ++c) {
    float4 xv = *(const float4*)(xb + (size_t)c * NPIX);
    float w0 = wr[0], w1 = wr[1], w2 = wr[2], w3 = wr[3];
    a0.x += xv.x * w0; a0.y += xv.y * w0; a0.z += xv.z * w0; a0.w += xv.w * w0;
    a1.x += xv.x * w1; a1.y += xv.y * w1; a1.z += xv.z * w1; a1.w += xv.w * w1;
    a2.x += xv.x * w2; a2.y += xv.y * w2; a2.z += xv.z * w2; a2.w += xv.w * w2;
    a3.x += xv.x * w3; a3.y += xv.y * w3; a3.z += xv.z * w3; a3.w += xv.w * w3;
    wr += Co;
  }
  __hip_bfloat16* yb = y + ((size_t)b * Co + d0) * NPIX + n;
  auto st4 = [](__hip_bfloat16* p, float4 v) {
    __hip_bfloat162 lo, hi;
    lo.x = __float2bfloat16(v.x); lo.y = __float2bfloat16(v.y);
    hi.x = __float2bfloat16(v.z); hi.y = __float2bfloat16(v.w);
    uint2 u; u.x = *(unsigned*)&lo; u.y = *(unsigned*)&hi;
    *(uint2*)p = u;
  };
  st4(yb, a0);
  st4(yb + NPIX, a1);
  st4(yb + 2 * (size_t)NPIX, a2);
  st4(yb + 3 * (size_t)NPIX, a3);
}

// ---------------------------------------------------------------------------
// f & g convs fused, output transposed + channel-padded to 32: [B][N][32] bf16
// 1 pixel/thread, input-channel loop unrolled x4 for load ILP.
// ---------------------------------------------------------------------------
template <int CF>
__global__ __launch_bounds__(256) void fg_convT_k(
    const float* __restrict__ xh, const float* __restrict__ wf, const float* __restrict__ bfv,
    const float* __restrict__ wg, const float* __restrict__ bgv,
    __hip_bfloat16* __restrict__ fqT, __hip_bfloat16* __restrict__ gqT, int Ci) {
  int n = blockIdx.x * 256 + threadIdx.x;
  int b = blockIdx.y;
  float fa[CF], ga[CF];
#pragma unroll
  for (int j = 0; j < CF; ++j) { fa[j] = bfv[j]; ga[j] = bgv[j]; }
  const float* xb = xh + ((size_t)b * Ci) * NPIX + n;
  for (int ci = 0; ci < Ci; ci += 4) {
    float x0 = xb[(size_t)(ci + 0) * NPIX];
    float x1 = xb[(size_t)(ci + 1) * NPIX];
    float x2 = xb[(size_t)(ci + 2) * NPIX];
    float x3 = xb[(size_t)(ci + 3) * NPIX];
#pragma unroll
    for (int j = 0; j < CF; ++j) {
      fa[j] += x0 * wf[(size_t)(ci + 0) * CF + j] + x1 * wf[(size_t)(ci + 1) * CF + j] +
               x2 * wf[(size_t)(ci + 2) * CF + j] + x3 * wf[(size_t)(ci + 3) * CF + j];
      ga[j] += x0 * wg[(size_t)(ci + 0) * CF + j] + x1 * wg[(size_t)(ci + 1) * CF + j] +
               x2 * wg[(size_t)(ci + 2) * CF + j] + x3 * wg[(size_t)(ci + 3) * CF + j];
    }
  }
  __align__(16) __hip_bfloat16 of[32];
  __align__(16) __hip_bfloat16 og[32];
#pragma unroll
  for (int j = 0; j < 32; ++j) {
    of[j] = __float2bfloat16(j < CF ? fa[j] : 0.f);
    og[j] = __float2bfloat16(j < CF ? ga[j] : 0.f);
  }
  uint4* df = (uint4*)(fqT + ((size_t)b * NPIX + n) * 32);
  uint4* dg = (uint4*)(gqT + ((size_t)b * NPIX + n) * 32);
#pragma unroll
  for (int k = 0; k < 4; ++k) { df[k] = ((uint4*)of)[k]; dg[k] = ((uint4*)og)[k]; }
}

// ---------------------------------------------------------------------------
// BN stats (float4 loads)
// ---------------------------------------------------------------------------
__global__ __launch_bounds__(256) void bn_stats_k(
    const float* __restrict__ y, float* __restrict__ mean, float* __restrict__ rstd, int C) {
  int c = blockIdx.x;
  int tid = threadIdx.x;
  float s = 0.f, s2 = 0.f;
  for (int i4 = tid; i4 < NB * NPIX / 4; i4 += 256) {
    int b = i4 >> 10;              // NPIX/4 = 1024
    int n = (i4 & 1023) * 4;
    float4 v = *(const float4*)&y[((size_t)b * C + c) * NPIX + n];
    s  += (v.x + v.y) + (v.z + v.w);
    s2 += (v.x * v.x + v.y * v.y) + (v.z * v.z + v.w * v.w);
  }
  __shared__ float sh0[256];
  __shared__ float sh1[256];
  sh0[tid] = s; sh1[tid] = s2;
  __syncthreads();
  for (int st = 128; st > 0; st >>= 1) {
    if (tid < st) { sh0[tid] += sh0[tid + st]; sh1[tid] += sh1[tid + st]; }
    __syncthreads();
  }
  if (tid == 0) {
    const float inv = 1.f / (NB * NPIX);
    float m = sh0[0] * inv;
    float var = sh1[0] * inv - m * m;
    mean[c] = m;
    rstd[c] = rsqrtf(var + 1e-5f);
  }
}

// ---------------------------------------------------------------------------
// BN apply + ReLU (float4)
// ---------------------------------------------------------------------------
__global__ __launch_bounds__(256) void bn_apply_k(
    const float* __restrict__ y, const float* __restrict__ mean, const float* __restrict__ rstd,
    const float* __restrict__ g, const float* __restrict__ bb, float* __restrict__ out, int C) {
  int i4 = blockIdx.x * 256 + threadIdx.x;
  int c = (i4 >> 10) % C;
  float sc = rstd[c] * g[c];
  float sb = bb[c] - mean[c] * sc;
  float4 v = *(const float4*)&y[(size_t)i4 * 4];
  v.x = fmaxf(v.x * sc + sb, 0.f);
  v.y = fmaxf(v.y * sc + sb, 0.f);
  v.z = fmaxf(v.z * sc + sb, 0.f);
  v.w = fmaxf(v.w * sc + sb, 0.f);
  *(float4*)&out[(size_t)i4 * 4] = v;
}

// ---------------------------------------------------------------------------
// MFMA flash attention partial (unchanged core; pacc now [MS][B][CO][N]).
// ---------------------------------------------------------------------------
template <int CO>
__global__ __launch_bounds__(256, 2) void attn_mfma_k(
    const __hip_bfloat16* __restrict__ fqT, const __hip_bfloat16* __restrict__ gqT,
    const __hip_bfloat16* __restrict__ hq,
    float* __restrict__ pacc, float* __restrict__ pl) {
  constexpr int CSUB   = CO / 16;
  constexpr int OPITCH = CO + 1;
  constexpr int PBYTES = 4 * QB * PPITCH * 2;
  constexpr int OBYTES = 4 * QB * OPITCH * 4;
  constexpr int SBYTES = PBYTES > OBYTES ? PBYTES : OBYTES;
  __shared__ __align__(16) char smem[SBYTES];
  __shared__ float l_red[4][QB];
  unsigned short* Pw = (unsigned short*)smem;
  float* Ored = (float*)smem;

  const int t = threadIdx.x;
  const int wave = t >> 6, lane = t & 63, lq = lane & 15, lg = lane >> 4;
  const int qblk = blockIdx.x, ms = blockIdx.y, b = blockIdx.z;
  const int q0 = qblk * QB;

  bf16x8 ff[2];
#pragma unroll
  for (int qs = 0; qs < 2; ++qs)
    ff[qs] = *reinterpret_cast<const bf16x8*>(
        fqT + (((size_t)b * NPIX + q0 + qs * 16 + lq) << 5) + lg * 8);

  f32x4 acc[2][CSUB];
#pragma unroll
  for (int qs = 0; qs < 2; ++qs)
#pragma unroll
    for (int cs = 0; cs < CSUB; ++cs) acc[qs][cs] = f32x4{0.f, 0.f, 0.f, 0.f};
  float ls[2] = {0.f, 0.f};

  unsigned short* Pmy = Pw + wave * QB * PPITCH;
  const __hip_bfloat16* hbase = hq + ((size_t)b * CO + lq) * NPIX + lg * 8;

  const int mbeg = ms * (NPIX / MS) + wave * TM;
  const int mend = (ms + 1) * (NPIX / MS);
  for (int mt = mbeg; mt < mend; mt += 4 * TM) {
#pragma unroll
    for (int msub = 0; msub < 4; ++msub) {
      bf16x8 ga = *reinterpret_cast<const bf16x8*>(
          gqT + (((size_t)b * NPIX + mt + msub * 16 + lq) << 5) + lg * 8);
#pragma unroll
      for (int qs = 0; qs < 2; ++qs) {
        f32x4 z = {0.f, 0.f, 0.f, 0.f};
        f32x4 S = __builtin_amdgcn_mfma_f32_16x16x32_bf16(ga, ff[qs], z, 0, 0, 0);
        float p0 = __expf(fminf(S[0], 60.f));
        float p1 = __expf(fminf(S[1], 60.f));
        float p2 = __expf(fminf(S[2], 60.f));
        float p3 = __expf(fminf(S[3], 60.f));
        ls[qs] += (p0 + p1) + (p2 + p3);
        __hip_bfloat162 t0, t1;
        t0.x = __float2bfloat16(p0); t0.y = __float2bfloat16(p1);
        t1.x = __float2bfloat16(p2); t1.y = __float2bfloat16(p3);
        uint2 wv;
        wv.x = *(unsigned*)&t0; wv.y = *(unsigned*)&t1;
        *(uint2*)(Pmy + (qs * 16 + lq) * PPITCH + msub * 16 + lg * 4) = wv;
      }
    }
#pragma unroll
    for (int kc = 0; kc < 2; ++kc) {
      bf16x8 pa[2];
#pragma unroll
      for (int qs = 0; qs < 2; ++qs)
        pa[qs] = *reinterpret_cast<const bf16x8*>(
            Pmy + (qs * 16 + lq) * PPITCH + kc * 32 + lg * 8);
      const __hip_bfloat16* hp = hbase + mt + kc * 32;
#pragma unroll
      for (int cs = 0; cs < CSUB; ++cs) {
        bf16x8 hv = *reinterpret_cast<const bf16x8*>(hp + (size_t)cs * 16 * NPIX);
#pragma unroll
        for (int qs = 0; qs < 2; ++qs)
          acc[qs][cs] = __builtin_amdgcn_mfma_f32_16x16x32_bf16(pa[qs], hv, acc[qs][cs], 0, 0, 0);
      }
    }
  }

#pragma unroll
  for (int qs = 0; qs < 2; ++qs) {
    float l = ls[qs];
    l += __shfl_xor(l, 16);
    l += __shfl_xor(l, 32);
    ls[qs] = l;
  }

  __syncthreads();
  if (lane < 16) { l_red[wave][lq] = ls[0]; l_red[wave][16 + lq] = ls[1]; }
#pragma unroll
  for (int qs = 0; qs < 2; ++qs)
#pragma unroll
    for (int cs = 0; cs < CSUB; ++cs)
#pragma unroll
      for (int r = 0; r < 4; ++r)
        Ored[((size_t)wave * QB + qs * 16 + 4 * lg + r) * OPITCH + cs * 16 + lq] = acc[qs][cs][r];
  __syncthreads();

  // pacc layout: [MS][B][CO][NPIX] (coalesced writes over q)
  const size_t obase = (((size_t)ms * NB + b) * CO) * NPIX + q0;
  for (int e = t; e < QB * CO; e += 256) {
    int c = e >> 5;          // QB = 32
    int q = e & 31;
    float o = Ored[((size_t)0 * QB + q) * OPITCH + c] + Ored[((size_t)1 * QB + q) * OPITCH + c] +
              Ored[((size_t)2 * QB + q) * OPITCH + c] + Ored[((size_t)3 * QB + q) * OPITCH + c];
    pacc[obase + (size_t)c * NPIX + q] = o;
  }
  if (t < QB) {
    pl[((size_t)ms * NB + b) * NPIX + q0 + t] =
        l_red[0][t] + l_red[1][t] + l_red[2][t] + l_red[3][t];
  }
}

// ---------------------------------------------------------------------------
// Attention combine: float4 streaming, coalesced. pacc [MS][B][CO][N].
// ---------------------------------------------------------------------------
template <int CO>
__global__ __launch_bounds__(256) void attn_combine2_k(
    const float* __restrict__ pacc, const float* __restrict__ pl,
    const float* __restrict__ xhat, const float* __restrict__ gam,
    float* __restrict__ xout) {
  int i4 = blockIdx.x * 256 + threadIdx.x;   // over NB*CO*NPIX/4
  int n  = (i4 & 1023) * 4;
  int bc = i4 >> 10;                          // b*CO + c
  int b  = bc / CO, c = bc - b * CO;
  float4 o = {0.f, 0.f, 0.f, 0.f};
  float4 L = {0.f, 0.f, 0.f, 0.f};
#pragma unroll
  for (int m = 0; m < MS; ++m) {
    float4 pa = *(const float4*)&pacc[(((size_t)m * NB + b) * CO + c) * NPIX + n];
    float4 lv = *(const float4*)&pl[((size_t)m * NB + b) * NPIX + n];
    o.x += pa.x; o.y += pa.y; o.z += pa.z; o.w += pa.w;
    L.x += lv.x; L.y += lv.y; L.z += lv.z; L.w += lv.w;
  }
  size_t xi = ((size_t)b * CO + c) * NPIX + n;
  float4 xh4 = *(const float4*)&xhat[xi];
  float gm = gam[0];
  float4 r;
  r.x = gm * (o.x / L.x) + xh4.x;
  r.y = gm * (o.y / L.y) + xh4.y;
  r.z = gm * (o.z / L.z) + xh4.z;
  r.w = gm * (o.w / L.w) + xh4.w;
  *(float4*)&xout[xi] = r;
}

// ---------------------------------------------------------------------------
// Final: BN apply + ReLU + GAP (float4)
// ---------------------------------------------------------------------------
__global__ __launch_bounds__(256) void bn_relu_gap_k(
    const float* __restrict__ y, const float* __restrict__ mean, const float* __restrict__ rstd,
    const float* __restrict__ g, const float* __restrict__ bb, float* __restrict__ out, int C) {
  int d = blockIdx.x;
  int b = blockIdx.y;
  int tid = threadIdx.x;
  const float* yr = y + ((size_t)b * C + d) * NPIX;
  float sc = rstd[d] * g[d];
  float sb = bb[d] - mean[d] * sc;
  float s = 0.f;
  for (int n4 = tid; n4 < NPIX / 4; n4 += 256) {
    float4 v = *(const float4*)&yr[n4 * 4];
    s += fmaxf(v.x * sc + sb, 0.f) + fmaxf(v.y * sc + sb, 0.f) +
         fmaxf(v.z * sc + sb, 0.f) + fmaxf(v.w * sc + sb, 0.f);
  }
  __shared__ float sh[256];
  sh[tid] = s;
  __syncthreads();
  for (int st = 128; st > 0; st >>= 1) {
    if (tid < st) sh[tid] += sh[tid + st];
    __syncthreads();
  }
  if (tid == 0) out[(size_t)b * C + d] = sh[0] * (1.f / NPIX);
}

// ---------------------------------------------------------------------------
// Host side
// ---------------------------------------------------------------------------
extern "C" void kernel_launch(void* const* d_in, const int* in_sizes, int n_in,
                              void* d_out, int out_size, void* d_ws, size_t ws_size,
                              hipStream_t stream) {
  const float* x    = (const float*)d_in[0];
  const float* wfin = (const float*)d_in[34];
  const float* bnfg = (const float*)d_in[35];
  const float* bnfb = (const float*)d_in[36];

  float* ws = (float*)d_ws;
  size_t off = 0;
  float* y    = ws + off; off += (size_t)NB * 512 * NPIX;
  float* xh   = ws + off; off += (size_t)NB * 96 * NPIX;
  float* xo   = ws + off; off += (size_t)NB * 96 * NPIX;
  __hip_bfloat16* fqT = (__hip_bfloat16*)(ws + off); off += (size_t)NB * NPIX * 16;
  __hip_bfloat16* gqT = (__hip_bfloat16*)(ws + off); off += (size_t)NB * NPIX * 16;
  __hip_bfloat16* hq  = (__hip_bfloat16*)(ws + off); off += (size_t)NB * 48 * NPIX;
  float* mean = ws + off; off += 512;
  float* rstd = ws + off; off += 512;
  float* pl   = ws + off; off += (size_t)MS * NB * NPIX;
  float* pacc = ws + off; off += (size_t)MS * NB * NPIX * 96;

  const int Ci_arr[3] = {3, 32, 64};
  const int Co_arr[3] = {32, 64, 96};
  const float* cur = x;
  for (int i = 0; i < 3; ++i) {
    const float* const* p = (const float* const*)(d_in + 1 + i * 11);
    const float* w     = p[0];
    const float* bconv = p[1];
    const float* bg    = p[2];
    const float* bbeta = p[3];
    const float* awf   = p[4];
    const float* abf   = p[5];
    const float* awg   = p[6];
    const float* abg   = p[7];
    const float* awh   = p[8];
    const float* abh   = p[9];
    const float* gam   = p[10];
    int Ci = Ci_arr[i], Co = Co_arr[i];

    conv1x1_k<<<dim3(NPIX / 1024, Co / 4, NB), 256, 0, stream>>>(cur, w, bconv, y, Ci, Co);
    bn_stats_k<<<Co, 256, 0, stream>>>(y, mean, rstd, Co);
    bn_apply_k<<<(NB * Co * NPIX) / 1024, 256, 0, stream>>>(y, mean, rstd, bg, bbeta, xh, Co);

    if (i == 0)      fg_convT_k<4><<<dim3(NPIX / 256, NB), 256, 0, stream>>>(xh, awf, abf, awg, abg, fqT, gqT, Co);
    else if (i == 1) fg_convT_k<8><<<dim3(NPIX / 256, NB), 256, 0, stream>>>(xh, awf, abf, awg, abg, fqT, gqT, Co);
    else             fg_convT_k<12><<<dim3(NPIX / 256, NB), 256, 0, stream>>>(xh, awf, abf, awg, abg, fqT, gqT, Co);

    conv_bf16_k<<<dim3(NPIX / 1024, Co / 4, NB), 256, 0, stream>>>(xh, awh, abh, hq, Co, Co);

    dim3 ag(NPIX / QB, MS, NB);
    if (Co == 32) {
      attn_mfma_k<32><<<ag, 256, 0, stream>>>(fqT, gqT, hq, pacc, pl);
      attn_combine2_k<32><<<(NB * 32 * NPIX) / 1024, 256, 0, stream>>>(pacc, pl, xh, gam, xo);
    } else if (Co == 64) {
      attn_mfma_k<64><<<ag, 256, 0, stream>>>(fqT, gqT, hq, pacc, pl);
      attn_combine2_k<64><<<(NB * 64 * NPIX) / 1024, 256, 0, stream>>>(pacc, pl, xh, gam, xo);
    } else {
      attn_mfma_k<96><<<ag, 256, 0, stream>>>(fqT, gqT, hq, pacc, pl);
      attn_combine2_k<96><<<(NB * 96 * NPIX) / 1024, 256, 0, stream>>>(pacc, pl, xh, gam, xo);
    }
    cur = xo;
  }

  conv1x1_k<<<dim3(NPIX / 1024, 512 / 4, NB), 256, 0, stream>>>(cur, wfin, nullptr, y, 96, 512);
  bn_stats_k<<<512, 256, 0, stream>>>(y, mean, rstd, 512);
  bn_relu_gap_k<<<dim3(512, NB), 256, 0, stream>>>(y, mean, rstd, bnfg, bnfb, (float*)d_out, 512);
}